// Round 12
// baseline (62.647 us; speedup 1.0000x reference)
//
#include <hip/hip_runtime.h>

// out = atoms_x - segment_mean(atoms_x, graph_batch)[graph_batch]
// graph_batch SORTED. Fused single pass, 4 INDEPENDENT waves/WG (r9), each
// wave owns a 512-atom chunk. ALL global access DENSE (16 lines per wave
// instr vs 64 chunked — the TA-transaction theory). Bank-exact LDS repack:
//   x  : word(k) = (k/24)*26 + k%24  -> chunked b64 reads (26l+2j)%32, 2-way (free)
//   ids: word(k) = k + k/8           -> chunked b32 reads (9l+j)%32, conflict-free
// Sum = r9's per-lane run accumulation (registers) + LDS slot atomics.
// Subtract: lanes write per-element means back into (dead) xbuf in chunked
// order, then dense read -> o = xr - mean, dense float4 stores.

static constexpr int WAVE   = 64;
static constexpr int WPB    = 4;                  // independent waves / WG
static constexpr int TPB    = WAVE * WPB;
static constexpr int CPT    = 8;                  // atoms per lane
static constexpr int WCHUNK = WAVE * CPT;         // 512 atoms per wave
static constexpr int SLOTS  = 64;                 // id-span (exp ~13)
static constexpr int XWORDS = (WCHUNK * 3 / 24) * 26;  // 1664 words
static constexpr int IWORDS = WCHUNK + WCHUNK / 8;     // 576 words

#define LDS_FENCE() asm volatile("s_waitcnt lgkmcnt(0)" ::: "memory")

__device__ __forceinline__ int xw(int k) { return (k / 24) * 26 + (k % 24); }

__device__ void serial_fallback(const float* __restrict__ x,
                                const int* __restrict__ gb,
                                float* __restrict__ out, int n,
                                long long cs, long long ce, int lane) {
  // Pathological id-sparsity; wave-uniform, never hot, correct.
  if (lane != 0) return;
  long long i = cs;
  while (i < ce) {
    int id = gb[i];
    long long rs = i; while (rs > 0 && gb[rs - 1] == id) --rs;
    long long re = i; while (re < n && gb[re] == id) ++re;
    float sx = 0.f, sy = 0.f, sz = 0.f;
    for (long long k = rs; k < re; ++k) {
      sx += x[k * 3 + 0]; sy += x[k * 3 + 1]; sz += x[k * 3 + 2];
    }
    float inv = 1.f / (float)(re - rs);
    float mx = sx * inv, my = sy * inv, mz = sz * inv;
    long long we = (re < ce) ? re : ce;
    for (long long k = i; k < we; ++k) {
      out[k * 3 + 0] = x[k * 3 + 0] - mx;
      out[k * 3 + 1] = x[k * 3 + 1] - my;
      out[k * 3 + 2] = x[k * 3 + 2] - mz;
    }
    i = we;
  }
}

__global__ __launch_bounds__(TPB) void fused_center_kernel(
    const float* __restrict__ x, const int* __restrict__ gb,
    float* __restrict__ out, int n) {
  __shared__ float xbuf_all[WPB][XWORDS];   // 6656 B / wave (x, then means)
  __shared__ int   ibuf_all[WPB][IWORDS];   // 2304 B / wave
  __shared__ float sums_all[WPB][SLOTS*4];  // 1024 B / wave

  const int w = threadIdx.x >> 6;
  const int lane = threadIdx.x & 63;
  float* xbuf = xbuf_all[w];
  int*   ibuf = ibuf_all[w];
  float* sums = sums_all[w];

  const long long cs = ((long long)blockIdx.x * WPB + w) * WCHUNK;
  if (cs >= (long long)n) return;  // idle wave; no __syncthreads anywhere
  const long long ce = (cs + WCHUNK < (long long)n) ? cs + WCHUNK : (long long)n;

  if (ce - cs < WCHUNK) {
    // ---- partial tail chunk (at most one wave in the grid) ----
    const int fid = gb[cs];
    const int lid = gb[ce - 1];
    const int span = lid - fid + 1;
    if (span > SLOTS) { serial_fallback(x, gb, out, n, cs, ce, lane); return; }
    for (int s = lane; s < span * 4; s += WAVE) sums[s] = 0.f;
    LDS_FENCE();
    for (long long i = cs + lane; i < ce; i += WAVE) {
      int s = (gb[i] - fid) * 4;
      atomicAdd(&sums[s + 0], x[i * 3 + 0]);
      atomicAdd(&sums[s + 1], x[i * 3 + 1]);
      atomicAdd(&sums[s + 2], x[i * 3 + 2]);
      atomicAdd(&sums[s + 3], 1.f);
    }
    if (cs > 0) {  // front halo only (ce == n here)
      float hx = 0.f, hy = 0.f, hz = 0.f, hc = 0.f;
      long long off = 1 + lane;
      for (;;) {
        long long i = cs - off;
        bool m = (i >= 0) && (gb[i] == fid);
        if (m) { hx += x[i*3+0]; hy += x[i*3+1]; hz += x[i*3+2]; hc += 1.f; }
        if (__popcll(__ballot(m)) < WAVE) break;
        off += WAVE;
      }
#pragma unroll
      for (int d = 1; d < 64; d <<= 1) {
        hx += __shfl_xor(hx, d); hy += __shfl_xor(hy, d);
        hz += __shfl_xor(hz, d); hc += __shfl_xor(hc, d);
      }
      if (lane == 0 && hc > 0.f) {
        atomicAdd(&sums[0], hx); atomicAdd(&sums[1], hy);
        atomicAdd(&sums[2], hz); atomicAdd(&sums[3], hc);
      }
    }
    LDS_FENCE();
    for (int s = lane; s < span; s += WAVE) {
      float c = sums[s * 4 + 3];
      if (c > 0.f) {
        float inv = 1.f / c;
        sums[s*4+0] *= inv; sums[s*4+1] *= inv; sums[s*4+2] *= inv;
      }
    }
    LDS_FENCE();
    for (long long i = cs + lane; i < ce; i += WAVE) {
      int s = (gb[i] - fid) * 4;
      out[i * 3 + 0] = x[i * 3 + 0] - sums[s + 0];
      out[i * 3 + 1] = x[i * 3 + 1] - sums[s + 1];
      out[i * 3 + 2] = x[i * 3 + 2] - sums[s + 2];
    }
    return;
  }

  // ---- dense global loads (16 lines / wave instruction) ----
  float4 xr[6];
  const float4* xv = reinterpret_cast<const float4*>(x + cs * 3);
#pragma unroll
  for (int j = 0; j < 6; ++j) xr[j] = xv[j * WAVE + lane];
  int4 gr[2];
  const int4* gv = reinterpret_cast<const int4*>(gb + cs);
#pragma unroll
  for (int j = 0; j < 2; ++j) gr[j] = gv[j * WAVE + lane];

  const int fid = __shfl(gr[0].x, 0);          // gb[cs]
  const int lid = __shfl(gr[1].w, WAVE - 1);   // gb[ce-1]
  const int span = lid - fid + 1;
  if (span > SLOTS) { serial_fallback(x, gb, out, n, cs, ce, lane); return; }

  // ---- stage to bank-exact padded LDS ----
#pragma unroll
  for (int j = 0; j < 6; ++j) {
    int k = (j * WAVE + lane) * 4;  // flat float index of this float4
    *reinterpret_cast<float2*>(&xbuf[xw(k)])     = make_float2(xr[j].x, xr[j].y);
    *reinterpret_cast<float2*>(&xbuf[xw(k + 2)]) = make_float2(xr[j].z, xr[j].w);
  }
#pragma unroll
  for (int j = 0; j < 2; ++j) {
    int k = (j * WAVE + lane) * 4;  // flat int index; k%8 in {0,4}
    int b = k + (k >> 3);
    ibuf[b + 0] = gr[j].x; ibuf[b + 1] = gr[j].y;
    ibuf[b + 2] = gr[j].z; ibuf[b + 3] = gr[j].w;
  }
  reinterpret_cast<float4*>(sums)[lane] = make_float4(0.f, 0.f, 0.f, 0.f);
  LDS_FENCE();

  // ---- chunked register views (conflict-free by construction) ----
  int idk[CPT];
#pragma unroll
  for (int j = 0; j < CPT; ++j) idk[j] = ibuf[9 * lane + j];
  float f[CPT * 3];
#pragma unroll
  for (int j = 0; j < 12; ++j) {
    float2 t = *reinterpret_cast<float2*>(&xbuf[26 * lane + 2 * j]);
    f[2*j] = t.x; f[2*j+1] = t.y;
  }

  // ---- per-lane run accumulation, flush at id boundaries ----
  {
    int cur = idk[0];
    float sx = 0.f, sy = 0.f, sz = 0.f, sc = 0.f;
#pragma unroll
    for (int j = 0; j < CPT; ++j) {
      if (idk[j] != cur) {
        int s = (cur - fid) * 4;
        atomicAdd(&sums[s + 0], sx); atomicAdd(&sums[s + 1], sy);
        atomicAdd(&sums[s + 2], sz); atomicAdd(&sums[s + 3], sc);
        cur = idk[j]; sx = sy = sz = sc = 0.f;
      }
      sx += f[j * 3 + 0]; sy += f[j * 3 + 1]; sz += f[j * 3 + 2]; sc += 1.f;
    }
    int s = (cur - fid) * 4;
    atomicAdd(&sums[s + 0], sx); atomicAdd(&sums[s + 1], sy);
    atomicAdd(&sums[s + 2], sz); atomicAdd(&sums[s + 3], sc);
  }

  // ---- halos: ballot-stepped probes complete edge molecules ----
  if (cs > 0) {
    float hx = 0.f, hy = 0.f, hz = 0.f, hc = 0.f;
    long long off = 1 + lane;
    for (;;) {
      long long i = cs - off;
      bool m = (i >= 0) && (gb[i] == fid);
      if (m) { hx += x[i*3+0]; hy += x[i*3+1]; hz += x[i*3+2]; hc += 1.f; }
      if (__popcll(__ballot(m)) < WAVE) break;
      off += WAVE;
    }
#pragma unroll
    for (int d = 1; d < 64; d <<= 1) {
      hx += __shfl_xor(hx, d); hy += __shfl_xor(hy, d);
      hz += __shfl_xor(hz, d); hc += __shfl_xor(hc, d);
    }
    if (lane == 0 && hc > 0.f) {
      atomicAdd(&sums[0], hx); atomicAdd(&sums[1], hy);
      atomicAdd(&sums[2], hz); atomicAdd(&sums[3], hc);
    }
  }
  if (ce < (long long)n) {
    float hx = 0.f, hy = 0.f, hz = 0.f, hc = 0.f;
    long long off = (long long)lane;
    for (;;) {
      long long i = ce + off;
      bool m = (i < (long long)n) && (gb[i] == lid);
      if (m) { hx += x[i*3+0]; hy += x[i*3+1]; hz += x[i*3+2]; hc += 1.f; }
      if (__popcll(__ballot(m)) < WAVE) break;
      off += WAVE;
    }
#pragma unroll
    for (int d = 1; d < 64; d <<= 1) {
      hx += __shfl_xor(hx, d); hy += __shfl_xor(hy, d);
      hz += __shfl_xor(hz, d); hc += __shfl_xor(hc, d);
    }
    if (lane == 0 && hc > 0.f) {
      int s = (lid - fid) * 4;
      atomicAdd(&sums[s + 0], hx); atomicAdd(&sums[s + 1], hy);
      atomicAdd(&sums[s + 2], hz); atomicAdd(&sums[s + 3], hc);
    }
  }
  LDS_FENCE();

  // ---- sums -> means (span <= 64: one slot per lane) ----
  if (lane < span) {
    float c = sums[lane * 4 + 3];
    if (c > 0.f) {
      float inv = 1.f / c;
      sums[lane*4+0] *= inv; sums[lane*4+1] *= inv; sums[lane*4+2] *= inv;
    }
  }
  LDS_FENCE();

  // ---- per-element means into (dead) xbuf, chunked order ----
  {
    float marr[CPT * 3];
    int prev = idk[0];
    float4 mv = *reinterpret_cast<float4*>(&sums[(prev - fid) * 4]);
#pragma unroll
    for (int j = 0; j < CPT; ++j) {
      if (idk[j] != prev) {
        prev = idk[j];
        mv = *reinterpret_cast<float4*>(&sums[(prev - fid) * 4]);
      }
      marr[3*j+0] = mv.x; marr[3*j+1] = mv.y; marr[3*j+2] = mv.z;
    }
#pragma unroll
    for (int j = 0; j < 12; ++j)
      *reinterpret_cast<float2*>(&xbuf[26 * lane + 2 * j]) =
          make_float2(marr[2*j], marr[2*j+1]);
  }
  LDS_FENCE();

  // ---- dense subtract + dense float4 stores ----
  float4* ov = reinterpret_cast<float4*>(out + cs * 3);
#pragma unroll
  for (int j = 0; j < 6; ++j) {
    int k = (j * WAVE + lane) * 4;
    float2 a = *reinterpret_cast<float2*>(&xbuf[xw(k)]);
    float2 b = *reinterpret_cast<float2*>(&xbuf[xw(k + 2)]);
    ov[j * WAVE + lane] = make_float4(xr[j].x - a.x, xr[j].y - a.y,
                                      xr[j].z - b.x, xr[j].w - b.y);
  }
}

extern "C" void kernel_launch(void* const* d_in, const int* in_sizes, int n_in,
                              void* d_out, int out_size, void* d_ws, size_t ws_size,
                              hipStream_t stream) {
  const float* x = (const float*)d_in[0];
  const int* gb = (const int*)d_in[1];
  float* out = (float*)d_out;
  const int n = in_sizes[0] / 3;  // atoms

  long long nchunks = ((long long)n + WCHUNK - 1) / WCHUNK;
  int blocks = (int)((nchunks + WPB - 1) / WPB);
  fused_center_kernel<<<blocks, TPB, 0, stream>>>(x, gb, out, n);
}

// Round 13
// 62.336 us; speedup vs baseline: 1.0050x; 1.0050x over previous
//
#include <hip/hip_runtime.h>

// out = atoms_x - segment_mean(atoms_x, graph_batch)[graph_batch]
// graph_batch SORTED. Fused single pass, 4 INDEPENDENT waves/WG, each wave
// owns a 512-atom chunk. ALL global access DENSE (16 lines per wave instr
// vs 64 chunked). LDS repack dense->chunked with an XOR swizzle
//   w' = w ^ (((w>>5)&7)<<2)
// which is conflict-free on dense ds_write_b128 (key constant per 32-word
// window -> quad permutation) and uniform (8 lanes/quad = optimal) on
// chunked ds_read_b128 (keys step by 3 mod 8 across the 16-lane class).
// Sum = per-lane run accumulation + LDS slot atomics (r9's cheap path).
// Subtract: per-element means written back into dead xbuf chunked, read
// dense, o = xr - m, dense float4 stores.

static constexpr int WAVE   = 64;
static constexpr int WPB    = 4;                  // independent waves / WG
static constexpr int TPB    = WAVE * WPB;
static constexpr int CPT    = 8;                  // atoms per lane
static constexpr int WCHUNK = WAVE * CPT;         // 512 atoms per wave
static constexpr int SLOTS  = 64;                 // id-span (exp ~13)
static constexpr int XWORDS = WCHUNK * 3;         // 1536 words
static constexpr int IWORDS = WCHUNK;             // 512 words

#define LDS_FENCE() asm volatile("s_waitcnt lgkmcnt(0)" ::: "memory")

__device__ __forceinline__ int swz(int w) {
  return w ^ (((w >> 5) & 7) << 2);  // XOR window-id into bank-quad bits
}

__device__ void serial_fallback(const float* __restrict__ x,
                                const int* __restrict__ gb,
                                float* __restrict__ out, int n,
                                long long cs, long long ce, int lane) {
  // Pathological id-sparsity; wave-uniform, never hot, correct.
  if (lane != 0) return;
  long long i = cs;
  while (i < ce) {
    int id = gb[i];
    long long rs = i; while (rs > 0 && gb[rs - 1] == id) --rs;
    long long re = i; while (re < n && gb[re] == id) ++re;
    float sx = 0.f, sy = 0.f, sz = 0.f;
    for (long long k = rs; k < re; ++k) {
      sx += x[k * 3 + 0]; sy += x[k * 3 + 1]; sz += x[k * 3 + 2];
    }
    float inv = 1.f / (float)(re - rs);
    float mx = sx * inv, my = sy * inv, mz = sz * inv;
    long long we = (re < ce) ? re : ce;
    for (long long k = i; k < we; ++k) {
      out[k * 3 + 0] = x[k * 3 + 0] - mx;
      out[k * 3 + 1] = x[k * 3 + 1] - my;
      out[k * 3 + 2] = x[k * 3 + 2] - mz;
    }
    i = we;
  }
}

__global__ __launch_bounds__(TPB) void fused_center_kernel(
    const float* __restrict__ x, const int* __restrict__ gb,
    float* __restrict__ out, int n) {
  __shared__ alignas(16) float xbuf_all[WPB][XWORDS];   // 6 KB / wave
  __shared__ alignas(16) int   ibuf_all[WPB][IWORDS];   // 2 KB / wave
  __shared__ alignas(16) float sums_all[WPB][SLOTS*4];  // 1 KB / wave

  const int w = threadIdx.x >> 6;
  const int lane = threadIdx.x & 63;
  float* xbuf = xbuf_all[w];
  int*   ibuf = ibuf_all[w];
  float* sums = sums_all[w];

  const long long cs = ((long long)blockIdx.x * WPB + w) * WCHUNK;
  if (cs >= (long long)n) return;  // idle wave; no __syncthreads anywhere
  const long long ce = (cs + WCHUNK < (long long)n) ? cs + WCHUNK : (long long)n;

  if (ce - cs < WCHUNK) {
    // ---- partial tail chunk (at most one wave in the grid) ----
    const int fid = gb[cs];
    const int lid = gb[ce - 1];
    const int span = lid - fid + 1;
    if (span > SLOTS) { serial_fallback(x, gb, out, n, cs, ce, lane); return; }
    for (int s = lane; s < span * 4; s += WAVE) sums[s] = 0.f;
    LDS_FENCE();
    for (long long i = cs + lane; i < ce; i += WAVE) {
      int s = (gb[i] - fid) * 4;
      atomicAdd(&sums[s + 0], x[i * 3 + 0]);
      atomicAdd(&sums[s + 1], x[i * 3 + 1]);
      atomicAdd(&sums[s + 2], x[i * 3 + 2]);
      atomicAdd(&sums[s + 3], 1.f);
    }
    if (cs > 0) {  // front halo only (ce == n here)
      float hx = 0.f, hy = 0.f, hz = 0.f, hc = 0.f;
      long long off = 1 + lane;
      for (;;) {
        long long i = cs - off;
        bool m = (i >= 0) && (gb[i] == fid);
        if (m) { hx += x[i*3+0]; hy += x[i*3+1]; hz += x[i*3+2]; hc += 1.f; }
        if (__popcll(__ballot(m)) < WAVE) break;
        off += WAVE;
      }
#pragma unroll
      for (int d = 1; d < 64; d <<= 1) {
        hx += __shfl_xor(hx, d); hy += __shfl_xor(hy, d);
        hz += __shfl_xor(hz, d); hc += __shfl_xor(hc, d);
      }
      if (lane == 0 && hc > 0.f) {
        atomicAdd(&sums[0], hx); atomicAdd(&sums[1], hy);
        atomicAdd(&sums[2], hz); atomicAdd(&sums[3], hc);
      }
    }
    LDS_FENCE();
    for (int s = lane; s < span; s += WAVE) {
      float c = sums[s * 4 + 3];
      if (c > 0.f) {
        float inv = 1.f / c;
        sums[s*4+0] *= inv; sums[s*4+1] *= inv; sums[s*4+2] *= inv;
      }
    }
    LDS_FENCE();
    for (long long i = cs + lane; i < ce; i += WAVE) {
      int s = (gb[i] - fid) * 4;
      out[i * 3 + 0] = x[i * 3 + 0] - sums[s + 0];
      out[i * 3 + 1] = x[i * 3 + 1] - sums[s + 1];
      out[i * 3 + 2] = x[i * 3 + 2] - sums[s + 2];
    }
    return;
  }

  // ---- dense global loads (16 lines / wave instruction) ----
  float4 xr[6];
  const float4* xv = reinterpret_cast<const float4*>(x + cs * 3);
#pragma unroll
  for (int j = 0; j < 6; ++j) xr[j] = xv[j * WAVE + lane];
  int4 gr[2];
  const int4* gv = reinterpret_cast<const int4*>(gb + cs);
#pragma unroll
  for (int j = 0; j < 2; ++j) gr[j] = gv[j * WAVE + lane];

  const int fid = __shfl(gr[0].x, 0);          // gb[cs]
  const int lid = __shfl(gr[1].w, WAVE - 1);   // gb[cs + 511]
  const int span = lid - fid + 1;
  if (span > SLOTS) { serial_fallback(x, gb, out, n, cs, ce, lane); return; }

  // ---- stage to swizzled LDS: dense b128 writes, conflict-free ----
#pragma unroll
  for (int j = 0; j < 6; ++j) {
    int wb = (j * WAVE + lane) * 4;
    *reinterpret_cast<float4*>(&xbuf[swz(wb)]) = xr[j];
  }
#pragma unroll
  for (int j = 0; j < 2; ++j) {
    int wb = (j * WAVE + lane) * 4;
    *reinterpret_cast<int4*>(&ibuf[swz(wb)]) = gr[j];
  }
  reinterpret_cast<float4*>(sums)[lane] = make_float4(0.f, 0.f, 0.f, 0.f);
  LDS_FENCE();

  // ---- chunked register views: swizzled b128 reads, uniform quads ----
  int idk[CPT];
  {
    int4 t0 = *reinterpret_cast<const int4*>(&ibuf[swz(8 * lane)]);
    int4 t1 = *reinterpret_cast<const int4*>(&ibuf[swz(8 * lane + 4)]);
    idk[0]=t0.x; idk[1]=t0.y; idk[2]=t0.z; idk[3]=t0.w;
    idk[4]=t1.x; idk[5]=t1.y; idk[6]=t1.z; idk[7]=t1.w;
  }
  float f[CPT * 3];
#pragma unroll
  for (int j = 0; j < 6; ++j) {
    float4 t = *reinterpret_cast<const float4*>(&xbuf[swz(24 * lane + 4 * j)]);
    f[4*j+0]=t.x; f[4*j+1]=t.y; f[4*j+2]=t.z; f[4*j+3]=t.w;
  }

  // ---- per-lane run accumulation, flush at id boundaries ----
  {
    int cur = idk[0];
    float sx = 0.f, sy = 0.f, sz = 0.f, sc = 0.f;
#pragma unroll
    for (int j = 0; j < CPT; ++j) {
      if (idk[j] != cur) {
        int s = (cur - fid) * 4;
        atomicAdd(&sums[s + 0], sx); atomicAdd(&sums[s + 1], sy);
        atomicAdd(&sums[s + 2], sz); atomicAdd(&sums[s + 3], sc);
        cur = idk[j]; sx = sy = sz = sc = 0.f;
      }
      sx += f[j * 3 + 0]; sy += f[j * 3 + 1]; sz += f[j * 3 + 2]; sc += 1.f;
    }
    int s = (cur - fid) * 4;
    atomicAdd(&sums[s + 0], sx); atomicAdd(&sums[s + 1], sy);
    atomicAdd(&sums[s + 2], sz); atomicAdd(&sums[s + 3], sc);
  }

  // ---- halos: ballot-stepped probes complete edge molecules ----
  if (cs > 0) {
    float hx = 0.f, hy = 0.f, hz = 0.f, hc = 0.f;
    long long off = 1 + lane;
    for (;;) {
      long long i = cs - off;
      bool m = (i >= 0) && (gb[i] == fid);
      if (m) { hx += x[i*3+0]; hy += x[i*3+1]; hz += x[i*3+2]; hc += 1.f; }
      if (__popcll(__ballot(m)) < WAVE) break;
      off += WAVE;
    }
#pragma unroll
    for (int d = 1; d < 64; d <<= 1) {
      hx += __shfl_xor(hx, d); hy += __shfl_xor(hy, d);
      hz += __shfl_xor(hz, d); hc += __shfl_xor(hc, d);
    }
    if (lane == 0 && hc > 0.f) {
      atomicAdd(&sums[0], hx); atomicAdd(&sums[1], hy);
      atomicAdd(&sums[2], hz); atomicAdd(&sums[3], hc);
    }
  }
  if (ce < (long long)n) {
    float hx = 0.f, hy = 0.f, hz = 0.f, hc = 0.f;
    long long off = (long long)lane;
    for (;;) {
      long long i = ce + off;
      bool m = (i < (long long)n) && (gb[i] == lid);
      if (m) { hx += x[i*3+0]; hy += x[i*3+1]; hz += x[i*3+2]; hc += 1.f; }
      if (__popcll(__ballot(m)) < WAVE) break;
      off += WAVE;
    }
#pragma unroll
    for (int d = 1; d < 64; d <<= 1) {
      hx += __shfl_xor(hx, d); hy += __shfl_xor(hy, d);
      hz += __shfl_xor(hz, d); hc += __shfl_xor(hc, d);
    }
    if (lane == 0 && hc > 0.f) {
      int s = (lid - fid) * 4;
      atomicAdd(&sums[s + 0], hx); atomicAdd(&sums[s + 1], hy);
      atomicAdd(&sums[s + 2], hz); atomicAdd(&sums[s + 3], hc);
    }
  }
  LDS_FENCE();

  // ---- sums -> means (span <= 64: one slot per lane) ----
  if (lane < span) {
    float c = sums[lane * 4 + 3];
    if (c > 0.f) {
      float inv = 1.f / c;
      sums[lane*4+0] *= inv; sums[lane*4+1] *= inv; sums[lane*4+2] *= inv;
    }
  }
  LDS_FENCE();

  // ---- per-element means into (dead) xbuf: chunked swizzled b128 writes ----
  {
    float marr[CPT * 3];
    int prev = idk[0];
    float4 mv = *reinterpret_cast<float4*>(&sums[(prev - fid) * 4]);
#pragma unroll
    for (int j = 0; j < CPT; ++j) {
      if (idk[j] != prev) {
        prev = idk[j];
        mv = *reinterpret_cast<float4*>(&sums[(prev - fid) * 4]);
      }
      marr[3*j+0] = mv.x; marr[3*j+1] = mv.y; marr[3*j+2] = mv.z;
    }
#pragma unroll
    for (int j = 0; j < 6; ++j) {
      float4 t = make_float4(marr[4*j+0], marr[4*j+1], marr[4*j+2], marr[4*j+3]);
      *reinterpret_cast<float4*>(&xbuf[swz(24 * lane + 4 * j)]) = t;
    }
  }
  LDS_FENCE();

  // ---- dense subtract + dense float4 stores ----
  float4* ov = reinterpret_cast<float4*>(out + cs * 3);
#pragma unroll
  for (int j = 0; j < 6; ++j) {
    int wb = (j * WAVE + lane) * 4;
    float4 m = *reinterpret_cast<const float4*>(&xbuf[swz(wb)]);
    ov[j * WAVE + lane] = make_float4(xr[j].x - m.x, xr[j].y - m.y,
                                      xr[j].z - m.z, xr[j].w - m.w);
  }
}

extern "C" void kernel_launch(void* const* d_in, const int* in_sizes, int n_in,
                              void* d_out, int out_size, void* d_ws, size_t ws_size,
                              hipStream_t stream) {
  const float* x = (const float*)d_in[0];
  const int* gb = (const int*)d_in[1];
  float* out = (float*)d_out;
  const int n = in_sizes[0] / 3;  // atoms

  long long nchunks = ((long long)n + WCHUNK - 1) / WCHUNK;
  int blocks = (int)((nchunks + WPB - 1) / WPB);
  fused_center_kernel<<<blocks, TPB, 0, stream>>>(x, gb, out, n);
}